// Round 3
// baseline (1290.516 us; speedup 1.0000x reference)
//
#include <hip/hip_runtime.h>
#include <stdint.h>

#define S_TOK 2048
#define D_NEU 11008
#define H_OUT 4096
#define K_TOK 3302
#define BASE_N 2201
#define K2_SEL 2201
#define NSEL 4402
#define NWORD 172          // D_NEU / 64

typedef __attribute__((ext_vector_type(8))) short short8;
typedef __attribute__((ext_vector_type(4))) short short4v;
typedef __attribute__((ext_vector_type(4))) float float4v;
typedef __attribute__((ext_vector_type(4))) unsigned int uint4v;
typedef unsigned long long u64;

__device__ __forceinline__ short f2bf(float x) {
  uint32_t u = __float_as_uint(x);
  u += 0x7FFFu + ((u >> 16) & 1u);
  return (short)(u >> 16);
}
__device__ __forceinline__ uint32_t fmap(float f) {
  uint32_t b = __float_as_uint(f);
  return (b & 0x80000000u) ? ~b : (b | 0x80000000u);
}

// ============ topk phase ablation: v1/v2/v3 monoliths all pinned at ~420us ===
// regardless of algorithm (bisection/radix), thread count (256/1024), VALU
// count (13%/5%), occupancy (7.5%/17.9%) -> split into 3 shallow stream
// kernels so rocprof localizes the wall per-phase. Selection math identical
// to v2/v3 (exact radix select, jax.lax.top_k tie semantics).

// ---- K1: read x row, fused bf16 convert, pass-0 (top byte) histogram ----
__global__ __launch_bounds__(256) void prep_hist(const float* __restrict__ x,
                                                 int* __restrict__ hist256,
                                                 short* __restrict__ xb) {
  __shared__ int hist[4][257];   // per-wave copies; stride 257 de-banks copies
  const int t = blockIdx.x, tid = threadIdx.x;
  const int wv = tid >> 6;
  const float* row = x + (size_t)t * D_NEU;
  int* hf = &hist[0][0];
  for (int b = tid; b < 4 * 257; b += 256) hf[b] = 0;
  __syncthreads();
  #pragma unroll
  for (int j = 0; j < 11; ++j) {
    int i4 = tid + j * 256;               // float4 index, 2752 total
    if (i4 < 2752) {
      float4v v = ((const float4v*)row)[i4];
      #pragma unroll
      for (int c = 0; c < 4; ++c)
        atomicAdd(&hist[wv][fmap(v[c]) >> 24], 1);
      if (xb) {
        short4v o;
        #pragma unroll
        for (int c = 0; c < 4; ++c) o[c] = f2bf(v[c]);
        *(short4v*)(xb + (size_t)t * D_NEU + i4 * 4) = o;
      }
    }
  }
  __syncthreads();
  hist256[t * 256 + tid] = hist[0][tid] + hist[1][tid] + hist[2][tid] + hist[3][tid];
}

// ---- K2: pick pass-0 bin from hist256, then radix passes 1..3 in LDS ----
__global__ __launch_bounds__(256) void select_thr(const float* __restrict__ x,
                                                  const int* __restrict__ hist256,
                                                  uint32_t* __restrict__ vstar_o,
                                                  int* __restrict__ ties_o,
                                                  int* __restrict__ eq_o) {
  __shared__ uint32_t u[D_NEU];     // 44032 B
  __shared__ int hist[4][257];
  __shared__ int bcast[4];
  const int t = blockIdx.x, tid = threadIdx.x;
  const int lane = tid & 63, wv = tid >> 6;
  const float* row = x + (size_t)t * D_NEU;

  // stage mapped row into LDS
  #pragma unroll
  for (int j = 0; j < 11; ++j) {
    int i4 = tid + j * 256;
    if (i4 < 2752) {
      float4v v = ((const float4v*)row)[i4];
      uint4v m;
      #pragma unroll
      for (int c = 0; c < 4; ++c) m[c] = fmap(v[c]);
      *(uint4v*)&u[i4 * 4] = m;
    }
  }
  // wave 0: pass-0 bin selection directly from the global histogram
  if (wv == 0) {
    int h0 = hist256[t * 256 + lane * 4 + 0];
    int h1 = hist256[t * 256 + lane * 4 + 1];
    int h2 = hist256[t * 256 + lane * 4 + 2];
    int h3 = hist256[t * 256 + lane * 4 + 3];
    int s = h0 + h1 + h2 + h3;
    int suf = s;                         // inclusive suffix scan across lanes
    #pragma unroll
    for (int off = 1; off < 64; off <<= 1) {
      int o = __shfl_down(suf, off);
      if (lane + off < 64) suf += o;
    }
    int S4 = suf - s;
    int S3 = h3 + S4;
    int S2 = h2 + S3;
    int S1 = h1 + S2;
    int S0 = h0 + S1;
    const int K0 = K_TOK;
    if (S0 >= K0 && S1 < K0)      { bcast[0] = lane * 4 + 0; bcast[1] = K0 - S1; bcast[2] = h0; }
    else if (S1 >= K0 && S2 < K0) { bcast[0] = lane * 4 + 1; bcast[1] = K0 - S2; bcast[2] = h1; }
    else if (S2 >= K0 && S3 < K0) { bcast[0] = lane * 4 + 2; bcast[1] = K0 - S3; bcast[2] = h2; }
    else if (S3 >= K0 && S4 < K0) { bcast[0] = lane * 4 + 3; bcast[1] = K0 - S4; bcast[2] = h3; }
  }
  __syncthreads();     // staging + bcast visible
  uint32_t prefix = ((uint32_t)bcast[0]) << 24;
  int K = bcast[1];
  int eq = bcast[2];
  int* hf = &hist[0][0];
  #pragma unroll
  for (int pass = 1; pass < 4; ++pass) {
    const int shift = 24 - 8 * pass;
    const uint32_t pm = 0xFFFFFFFFu << (shift + 8);
    for (int b = tid; b < 4 * 257; b += 256) hf[b] = 0;
    __syncthreads();
    #pragma unroll
    for (int j = 0; j < 11; ++j) {
      int i4 = tid + j * 256;
      if (i4 < 2752) {
        uint4v m = *(const uint4v*)&u[i4 * 4];
        #pragma unroll
        for (int c = 0; c < 4; ++c)
          if ((m[c] & pm) == prefix)
            atomicAdd(&hist[wv][(m[c] >> shift) & 255], 1);
      }
    }
    __syncthreads();
    if (wv == 0) {
      int h0 = hist[0][lane * 4 + 0] + hist[1][lane * 4 + 0] + hist[2][lane * 4 + 0] + hist[3][lane * 4 + 0];
      int h1 = hist[0][lane * 4 + 1] + hist[1][lane * 4 + 1] + hist[2][lane * 4 + 1] + hist[3][lane * 4 + 1];
      int h2 = hist[0][lane * 4 + 2] + hist[1][lane * 4 + 2] + hist[2][lane * 4 + 2] + hist[3][lane * 4 + 2];
      int h3 = hist[0][lane * 4 + 3] + hist[1][lane * 4 + 3] + hist[2][lane * 4 + 3] + hist[3][lane * 4 + 3];
      int s = h0 + h1 + h2 + h3;
      int suf = s;
      #pragma unroll
      for (int off = 1; off < 64; off <<= 1) {
        int o = __shfl_down(suf, off);
        if (lane + off < 64) suf += o;
      }
      int S4 = suf - s;
      int S3 = h3 + S4;
      int S2 = h2 + S3;
      int S1 = h1 + S2;
      int S0 = h0 + S1;
      if (S0 >= K && S1 < K)      { bcast[0] = lane * 4 + 0; bcast[1] = K - S1; bcast[2] = h0; }
      else if (S1 >= K && S2 < K) { bcast[0] = lane * 4 + 1; bcast[1] = K - S2; bcast[2] = h1; }
      else if (S2 >= K && S3 < K) { bcast[0] = lane * 4 + 2; bcast[1] = K - S3; bcast[2] = h2; }
      else if (S3 >= K && S4 < K) { bcast[0] = lane * 4 + 3; bcast[1] = K - S4; bcast[2] = h3; }
    }
    __syncthreads();
    prefix |= ((uint32_t)bcast[0]) << shift;
    K = bcast[1];
    eq = bcast[2];
  }
  if (tid == 0) {
    vstar_o[t] = prefix;   // exact k-th largest (mapped)
    ties_o[t] = K;         // equals to include
    eq_o[t] = eq;          // total equals
  }
}

// ---- K3: membership ballot -> bitmask (pure stream) ----
__global__ __launch_bounds__(256) void ballot_phase(const float* __restrict__ x,
                                                    const uint32_t* __restrict__ vstar_i,
                                                    const int* __restrict__ ties_i,
                                                    const int* __restrict__ eq_i,
                                                    u64* __restrict__ bitmask) {
  const int t = blockIdx.x, tid = threadIdx.x;
  const int lane = tid & 63, wv = tid >> 6;
  const uint32_t vstar = vstar_i[t];
  const int ties = ties_i[t];
  const bool tie_all = (ties == eq_i[t]);
  const float* row = x + (size_t)t * D_NEU;
  for (int w = wv; w < NWORD; w += 4) {
    uint32_t uu = fmap(row[w * 64 + lane]);
    bool m = false;
    if (uu > vstar) m = true;
    else if (uu == vstar) {
      if (tie_all) m = true;
      else {                              // rare exact-tie path
        int idx = w * 64 + lane, r = 0;
        for (int i = 0; i < idx; ++i) r += (fmap(row[i]) == vstar) ? 1 : 0;
        m = (r < ties);
      }
    }
    u64 mask = __ballot(m);
    if (lane == 0) bitmask[(size_t)w * S_TOK + t] = mask;
  }
}

// ---------------- counts[d] = sum_t bit(t,d) ----------------
__global__ __launch_bounds__(256) void count_bits(const u64* __restrict__ bitmask,
                                                  int* __restrict__ counts) {
  __shared__ u64 m[S_TOK];        // 16 KB
  __shared__ int partial[4][64];
  const int w = blockIdx.x, tid = threadIdx.x;
  for (int i = tid; i < S_TOK; i += 256) m[i] = bitmask[(size_t)w * S_TOK + i];
  __syncthreads();
  const int b = tid & 63, part = tid >> 6;
  int c = 0;
  for (int t = part * 512; t < part * 512 + 512; ++t) c += (int)((m[t] >> b) & 1ull);
  partial[part][b] = c;
  __syncthreads();
  if (tid < 64)
    counts[w * 64 + tid] = partial[0][tid] + partial[1][tid] + partial[2][tid] + partial[3][tid];
}

// ---------------- rank candidates, select top-2201, emit idx_all ----------------
// keys are DISTINCT (count<<14 | reversed-id)+1, so the 2201st-largest key is
// found by bisection, the winners compacted, and only 4096 sorted bitonically.
__global__ __launch_bounds__(1024) void rank_select(const int* __restrict__ counts,
                                                    int* __restrict__ idx_all) {
  __shared__ uint32_t cand[4096];   // 16 KB
  __shared__ int red[16];
  __shared__ int cnt_sh;
  const int tid = threadIdx.x, lane = tid & 63, wv = tid >> 6;
  const int NC = D_NEU - BASE_N;    // 8807
  uint32_t kv[9];
  #pragma unroll
  for (int j = 0; j < 9; ++j) {
    int i = tid + j * 1024;
    kv[j] = 0u;
    if (i < NC) {
      int d = BASE_N + i;
      kv[j] = ((((uint32_t)counts[d]) << 14) | (uint32_t)(D_NEU - 1 - d)) + 1u;
    }
  }
  auto cnt_ge = [&](uint32_t T) -> int {
    int c = 0;
    #pragma unroll
    for (int j = 0; j < 9; ++j) c += (kv[j] >= T) ? 1 : 0;
    #pragma unroll
    for (int off = 32; off; off >>= 1) c += __shfl_down(c, off);
    if (lane == 0) red[wv] = c;
    __syncthreads();
    int tot = 0;
    #pragma unroll
    for (int k = 0; k < 16; ++k) tot += red[k];
    __syncthreads();
    return tot;
  };
  uint32_t lo = 0u, hi = 1u << 26;
  while (hi - lo > 1u) {
    uint32_t mid = lo + ((hi - lo) >> 1);
    if (cnt_ge(mid) >= K2_SEL) lo = mid; else hi = mid;
  }
  if (tid == 0) cnt_sh = 0;
  for (int i = tid; i < 4096; i += 1024) cand[i] = 0u;
  __syncthreads();
  #pragma unroll
  for (int j = 0; j < 9; ++j)
    if (kv[j] >= lo && kv[j] != 0u) { int p = atomicAdd(&cnt_sh, 1); cand[p] = kv[j]; }
  __syncthreads();
  // bitonic sort 4096 descending
  for (unsigned size = 2; size <= 4096u; size <<= 1) {
    for (unsigned stride = size >> 1; stride > 0; stride >>= 1) {
      #pragma unroll
      for (unsigned tt = tid; tt < 2048u; tt += 1024u) {
        unsigned li = ((tt & ~(stride - 1u)) << 1) | (tt & (stride - 1u));
        unsigned hi2 = li + stride;
        uint32_t a = cand[li], b = cand[hi2];
        bool desc = ((li & size) == 0u);
        if (desc ? (a < b) : (a > b)) { cand[li] = b; cand[hi2] = a; }
      }
      __syncthreads();
    }
  }
  for (int j = tid; j < BASE_N; j += 1024) idx_all[j] = j;
  for (int j = tid; j < K2_SEL; j += 1024)
    idx_all[BASE_N + j] = (D_NEU - 1) - (int)((cand[j] - 1u) & 0x3FFFu);
}

// ---------------- fused W pass: W->bf16 + gather filtered_W ----------------
__global__ __launch_bounds__(256) void fused_w(const float* __restrict__ W,
                                               const int* __restrict__ idx_all,
                                               short* __restrict__ Wb,
                                               float* __restrict__ out2) {
  __shared__ float row[D_NEU];    // 44 KB
  const int h = blockIdx.x, tid = threadIdx.x;
  const float* src = W + (size_t)h * D_NEU;
  #pragma unroll
  for (int j = 0; j < 11; ++j) {
    int i4 = tid + j * 256;
    if (i4 < 2752) {
      float4v v = ((const float4v*)src)[i4];
      *(float4v*)&row[i4 * 4] = v;
      if (Wb) {
        short4v o;
        #pragma unroll
        for (int c = 0; c < 4; ++c) o[c] = f2bf(v[c]);
        *(short4v*)(Wb + (size_t)h * D_NEU + i4 * 4) = o;
      }
    }
  }
  __syncthreads();
  for (int j = tid; j < NSEL; j += 256)
    out2[(size_t)h * NSEL + j] = row[idx_all[j]];
}

// ---------------- bf16 MFMA GEMM, split-K=2, XOR chunk-swizzle ----------------
#define BM 128
#define BN 128
#define BKK 32
#define KSPLIT 2
#define KHALF (D_NEU / KSPLIT)   // 5504 = 172 * 32

template <int FROM_FP32>
__global__ __launch_bounds__(256) void gemm_bt(const void* __restrict__ Av,
                                               const void* __restrict__ Bv,
                                               float* __restrict__ C) {
  __shared__ __align__(16) short As[BM * BKK];   // 8 KB
  __shared__ __align__(16) short Bs[BN * BKK];   // 8 KB
  const int tid = threadIdx.x;
  const int bm = blockIdx.y * BM;
  const int bn = blockIdx.x * BN;
  const int kz = blockIdx.z;
  const int wave = tid >> 6, lane = tid & 63;
  const int wm = (wave >> 1) * 64, wn = (wave & 1) * 64;
  const int quad = lane >> 4, l16 = lane & 15;
  float4v acc[4][4];
  #pragma unroll
  for (int i = 0; i < 4; ++i)
    #pragma unroll
    for (int j = 0; j < 4; ++j) acc[i][j] = (float4v){0.f, 0.f, 0.f, 0.f};

  const int kbeg = kz * KHALF, kend = kbeg + KHALF;
  for (int k0 = kbeg; k0 < kend; k0 += BKK) {
    #pragma unroll
    for (int c = 0; c < 2; ++c) {
      int f = tid + c * 256;            // LDS 16B-slot id (512/tile)
      int r = f >> 2, sl = f & 3;
      int cg = sl ^ (r & 3);            // swizzled global chunk
      if (FROM_FP32) {
        const float* A = (const float*)Av;
        const float* B = (const float*)Bv;
        float4v v0 = *(const float4v*)(A + (size_t)(bm + r) * D_NEU + k0 + cg * 8);
        float4v v1 = *(const float4v*)(A + (size_t)(bm + r) * D_NEU + k0 + cg * 8 + 4);
        short8 o;
        #pragma unroll
        for (int c2 = 0; c2 < 4; ++c2) { o[c2] = f2bf(v0[c2]); o[c2+4] = f2bf(v1[c2]); }
        *(short8*)&As[f * 8] = o;
        v0 = *(const float4v*)(B + (size_t)(bn + r) * D_NEU + k0 + cg * 8);
        v1 = *(const float4v*)(B + (size_t)(bn + r) * D_NEU + k0 + cg * 8 + 4);
        #pragma unroll
        for (int c2 = 0; c2 < 4; ++c2) { o[c2] = f2bf(v0[c2]); o[c2+4] = f2bf(v1[c2]); }
        *(short8*)&Bs[f * 8] = o;
      } else {
        const short* A = (const short*)Av;
        const short* B = (const short*)Bv;
        __builtin_amdgcn_global_load_lds(
            (const __attribute__((address_space(1))) void*)(A + (size_t)(bm + r) * D_NEU + k0 + cg * 8),
            (__attribute__((address_space(3))) void*)&As[f * 8], 16, 0, 0);
        __builtin_amdgcn_global_load_lds(
            (const __attribute__((address_space(1))) void*)(B + (size_t)(bn + r) * D_NEU + k0 + cg * 8),
            (__attribute__((address_space(3))) void*)&Bs[f * 8], 16, 0, 0);
      }
    }
    __syncthreads();
    short8 af[4], bfv[4];
    #pragma unroll
    for (int i = 0; i < 4; ++i) {
      int ra = wm + i * 16 + l16;
      int rb = wn + i * 16 + l16;
      af[i]  = *(const short8*)&As[(ra * 4 + (quad ^ (ra & 3))) * 8];
      bfv[i] = *(const short8*)&Bs[(rb * 4 + (quad ^ (rb & 3))) * 8];
    }
    #pragma unroll
    for (int i = 0; i < 4; ++i)
      #pragma unroll
      for (int j = 0; j < 4; ++j)
        acc[i][j] = __builtin_amdgcn_mfma_f32_16x16x32_bf16(af[i], bfv[j], acc[i][j], 0, 0, 0);
    __syncthreads();
  }
  // C/D layout: col = lane&15, row = quad*4 + reg  [m89-verified]
  #pragma unroll
  for (int i = 0; i < 4; ++i)
    #pragma unroll
    for (int j = 0; j < 4; ++j)
      #pragma unroll
      for (int r = 0; r < 4; ++r)
        unsafeAtomicAdd(
            &C[(size_t)(bm + wm + i * 16 + quad * 4 + r) * H_OUT + (bn + wn + j * 16 + l16)],
            acc[i][j][r]);
}

extern "C" void kernel_launch(void* const* d_in, const int* in_sizes, int n_in,
                              void* d_out, int out_size, void* d_ws, size_t ws_size,
                              hipStream_t stream) {
  (void)in_sizes; (void)n_in; (void)out_size;
  const float* x = (const float*)d_in[0];   // [1, 2048, 11008]
  const float* W = (const float*)d_in[1];   // [4096, 11008]
  float* out1 = (float*)d_out;                       // true_value [2048*4096]
  float* out2 = out1 + (size_t)S_TOK * H_OUT;        // filtered_W [4096*4402]

  uint8_t* ws = (uint8_t*)d_ws;
  int* idx_all = (int*)ws;                              // 17608 B
  int* counts  = (int*)(ws + 17664);                    // 44032 B
  short* xb = (short*)(ws + 65536);                     // 45,088,768 B
  short* Wb = xb + (size_t)S_TOK * D_NEU;               // 90,177,536 B
  const size_t needA = 65536 + ((size_t)S_TOK + H_OUT) * D_NEU * 2;
  const bool pathA = ws_size >= needA;
  // scratch (bitmask 2.82 MB + hist256 2 MB + vstar/ties/eq 24 KB) aliases the
  // Wb region: all of it is fully consumed (by select_thr/ballot_phase/
  // count_bits) before fused_w writes Wb (single in-order stream).
  uint8_t* alias = pathA ? (uint8_t*)Wb : (ws + 65536);
  u64* bitmask = (u64*)alias;                           // 2,818,048 B
  int* hist256 = (int*)(alias + 2818048);               // 2,097,152 B
  uint32_t* vstar_b = (uint32_t*)(alias + 4915200);     // 8192 B
  int* ties_b = (int*)(alias + 4923392);                // 8192 B
  int* eq_b   = (int*)(alias + 4931584);                // 8192 B

  hipMemsetAsync(out1, 0, (size_t)S_TOK * H_OUT * sizeof(float), stream);
  prep_hist<<<S_TOK, 256, 0, stream>>>(x, hist256, pathA ? xb : nullptr);
  select_thr<<<S_TOK, 256, 0, stream>>>(x, hist256, vstar_b, ties_b, eq_b);
  ballot_phase<<<S_TOK, 256, 0, stream>>>(x, vstar_b, ties_b, eq_b, bitmask);
  count_bits<<<NWORD, 256, 0, stream>>>(bitmask, counts);
  rank_select<<<1, 1024, 0, stream>>>(counts, idx_all);
  fused_w<<<H_OUT, 256, 0, stream>>>(W, idx_all, pathA ? Wb : nullptr, out2);
  if (pathA)
    gemm_bt<0><<<dim3(H_OUT / BN, S_TOK / BM, KSPLIT), 256, 0, stream>>>(xb, Wb, out1);
  else
    gemm_bt<1><<<dim3(H_OUT / BN, S_TOK / BM, KSPLIT), 256, 0, stream>>>(x, W, out1);
}